// Round 1
// baseline (1061.250 us; speedup 1.0000x reference)
//
#include <hip/hip_runtime.h>

#define NNODES 50000
#define NEDGES 800000
#define HDIM 64
#define GAMMA 0.2f

__device__ __forceinline__ float wave_sum(float v) {
    #pragma unroll
    for (int off = 32; off; off >>= 1) v += __shfl_xor(v, off, 64);
    return v;
}
__device__ __forceinline__ float wave_max(float v) {
    #pragma unroll
    for (int off = 32; off; off >>= 1) v = fmaxf(v, __shfl_xor(v, off, 64));
    return v;
}

// ws[k] = sum_j W_fc[j,k] * a_src[j] ; wd[k] = sum_j W_fc[j,k] * a_dst[j]
__global__ void k_wswd(const float* __restrict__ Wfc, const float* __restrict__ attn,
                       float* __restrict__ ws, float* __restrict__ wd) {
    int k = threadIdx.x; // 64 threads
    float s = 0.f, d = 0.f;
    for (int j = 0; j < HDIM; ++j) {
        float w = Wfc[j * HDIM + k];
        s += w * attn[j];
        d += w * attn[HDIM + j];
    }
    ws[k] = s; wd[k] = d;
}

// zs[n] = h[n]·ws, zd[n] = h[n]·wd  (wave per node)
__global__ __launch_bounds__(256) void k_zinit(const float* __restrict__ h,
                                               const float* __restrict__ ws,
                                               const float* __restrict__ wd,
                                               float* __restrict__ zs, float* __restrict__ zd) {
    int wid = (blockIdx.x * blockDim.x + threadIdx.x) >> 6;
    int lane = threadIdx.x & 63;
    if (wid >= NNODES) return;
    float v = h[wid * HDIM + lane];
    float a = wave_sum(v * ws[lane]);
    float b = wave_sum(v * wd[lane]);
    if (lane == 0) { zs[wid] = a; zd[wid] = b; }
}

__global__ __launch_bounds__(256) void k_count(const int* __restrict__ dst, int* __restrict__ deg) {
    int k = blockIdx.x * blockDim.x + threadIdx.x;
    if (k < NEDGES) atomicAdd(&deg[dst[k]], 1);
}

// single-block exclusive scan of deg -> row_ptr, cursor
__global__ __launch_bounds__(1024) void k_scan(const int* __restrict__ deg,
                                               int* __restrict__ row_ptr, int* __restrict__ cursor) {
    __shared__ int sums[1024];
    int t = threadIdx.x;
    const int per = (NNODES + 1023) / 1024;
    int lo = t * per, hi = min(lo + per, NNODES);
    int s = 0;
    for (int i = lo; i < hi; ++i) s += deg[i];
    sums[t] = s;
    __syncthreads();
    for (int off = 1; off < 1024; off <<= 1) {
        int v = (t >= off) ? sums[t - off] : 0;
        __syncthreads();
        sums[t] += v;
        __syncthreads();
    }
    int run = (t > 0) ? sums[t - 1] : 0;
    for (int i = lo; i < hi; ++i) {
        row_ptr[i] = run; cursor[i] = run;
        run += deg[i];
    }
    if (t == 0) row_ptr[NNODES] = NEDGES;
}

__global__ __launch_bounds__(256) void k_fill(const int* __restrict__ src, const int* __restrict__ dst,
                                              int* __restrict__ cursor, int* __restrict__ csr_src) {
    int k = blockIdx.x * blockDim.x + threadIdx.x;
    if (k >= NEDGES) return;
    int d = dst[k];
    int pos = atomicAdd(&cursor[d], 1);
    csr_src[pos] = src[k];
}

// One wave per node: segment softmax over incoming edges + crf gather + h update.
// Optionally stores att (last layer) and next-layer zs/zd.
template <bool STORE_ATT, bool COMPUTE_Z>
__global__ __launch_bounds__(256) void k_layer(const float* __restrict__ h_in,
                                               const float* __restrict__ emb,
                                               const int* __restrict__ row_ptr,
                                               const int* __restrict__ csr_src,
                                               const float* __restrict__ zs,
                                               const float* __restrict__ zd,
                                               float* __restrict__ att_csr,
                                               float* __restrict__ h_out,
                                               const float* __restrict__ ws,
                                               const float* __restrict__ wd,
                                               float* __restrict__ zs_out,
                                               float* __restrict__ zd_out) {
    int wid = (blockIdx.x * blockDim.x + threadIdx.x) >> 6;
    int lane = threadIdx.x & 63;
    if (wid >= NNODES) return;
    int s0 = row_ptr[wid], s1 = row_ptr[wid + 1];
    float zdn = zd[wid];

    // phase 1: max of leaky(e)
    float m = -INFINITY;
    for (int base = s0; base < s1; base += 64) {
        int i = base + lane;
        if (i < s1) {
            int s = csr_src[i];
            float e = zs[s] + zdn;
            e = e > 0.f ? e : GAMMA * e;
            m = fmaxf(m, e);
        }
    }
    m = wave_max(m);
    // phase 2: denom
    float dsum = 0.f;
    for (int base = s0; base < s1; base += 64) {
        int i = base + lane;
        if (i < s1) {
            int s = csr_src[i];
            float e = zs[s] + zdn;
            e = e > 0.f ? e : GAMMA * e;
            dsum += __expf(e - m);
        }
    }
    dsum = wave_sum(dsum);
    float inv = 1.f / fmaxf(dsum, 1e-16f);
    // phase 3: crf accumulate (lane = feature dim)
    float acc = 0.f;
    for (int base = s0; base < s1; base += 64) {
        int i = base + lane;
        float ex = 0.f; int s = 0;
        if (i < s1) {
            s = csr_src[i];
            float e = zs[s] + zdn;
            e = e > 0.f ? e : GAMMA * e;
            ex = __expf(e - m);
            if (STORE_ATT) att_csr[i] = ex * inv;
        }
        int ne = min(64, s1 - base);
        for (int j = 0; j < ne; ++j) {
            float w = __shfl(ex, j, 64);
            int sj = __shfl(s, j, 64);
            acc += w * h_in[sj * HDIM + lane];
        }
    }
    acc *= inv;
    float hv = 0.5f * (emb[wid * HDIM + lane] + acc);
    h_out[wid * HDIM + lane] = hv;
    if (COMPUTE_Z) {
        float a = wave_sum(hv * ws[lane]);
        float b = wave_sum(hv * wd[lane]);
        if (lane == 0) { zs_out[wid] = a; zd_out[wid] = b; }
    }
}

__global__ __launch_bounds__(256) void k_loss(const float* __restrict__ h,
                                              const float* __restrict__ emb,
                                              const int* __restrict__ row_ptr,
                                              const int* __restrict__ csr_src,
                                              const float* __restrict__ att_csr,
                                              float* __restrict__ acc) {
    int wid = (blockIdx.x * blockDim.x + threadIdx.x) >> 6;
    int lane = threadIdx.x & 63;
    if (wid >= NNODES) return;
    float hv = h[wid * HDIM + lane];
    float ev = emb[wid * HDIM + lane];
    float d0 = hv - ev;
    float la = wave_sum(d0 * d0);
    float lb = 0.f;
    int s0 = row_ptr[wid], s1 = row_ptr[wid + 1];
    for (int base = s0; base < s1; base += 64) {
        int i = base + lane;
        int s = 0; float att = 0.f;
        if (i < s1) { s = csr_src[i]; att = att_csr[i]; }
        int ne = min(64, s1 - base);
        for (int j = 0; j < ne; ++j) {
            int sj = __shfl(s, j, 64);
            float aj = __shfl(att, j, 64);
            float dd = hv - h[sj * HDIM + lane];
            float ss = wave_sum(dd * dd);
            lb += aj * sqrtf(ss + 1e-12f);
        }
    }
    if (lane == 0) atomicAdd(acc, 0.5f * la + 0.5f * lb);
}

__global__ void k_finalize(const float* __restrict__ acc, float* __restrict__ out_loss) {
    out_loss[0] = acc[0] / (float)NNODES;
}

extern "C" void kernel_launch(void* const* d_in, const int* in_sizes, int n_in,
                              void* d_out, int out_size, void* d_ws, size_t ws_size,
                              hipStream_t stream) {
    const float* emb  = (const float*)d_in[0];
    const float* Wfc  = (const float*)d_in[1];
    const float* attn = (const float*)d_in[2];
    const int*   src  = (const int*)d_in[3];
    const int*   dst  = (const int*)d_in[4];
    float* out = (float*)d_out; // [N*H] h, then [1] loss

    char* p = (char*)d_ws;
    int*   deg     = (int*)p;   p += (size_t)NNODES * 4;
    int*   cursor  = (int*)p;   p += (size_t)NNODES * 4;
    int*   row_ptr = (int*)p;   p += (size_t)(NNODES + 1) * 4;
    p = (char*)(((size_t)p + 255) & ~(size_t)255);
    int*   csr_src = (int*)p;   p += (size_t)NEDGES * 4;
    float* att_csr = (float*)p; p += (size_t)NEDGES * 4;
    float* zs0     = (float*)p; p += (size_t)NNODES * 4;
    float* zd0     = (float*)p; p += (size_t)NNODES * 4;
    float* zs1     = (float*)p; p += (size_t)NNODES * 4;
    float* zd1     = (float*)p; p += (size_t)NNODES * 4;
    float* wsv     = (float*)p; p += 64 * 4;
    float* wdv     = (float*)p; p += 64 * 4;
    float* lossAcc = (float*)p; p += 256;
    p = (char*)(((size_t)p + 255) & ~(size_t)255);
    float* h1      = (float*)p; p += (size_t)NNODES * HDIM * 4;

    hipMemsetAsync(deg, 0, (size_t)NNODES * 4, stream);
    hipMemsetAsync(lossAcc, 0, 4, stream);

    const int EB = (NEDGES + 255) / 256;
    const int NB = (NNODES * HDIM + 255) / 256;

    k_wswd<<<1, 64, 0, stream>>>(Wfc, attn, wsv, wdv);
    k_count<<<EB, 256, 0, stream>>>(dst, deg);
    k_scan<<<1, 1024, 0, stream>>>(deg, row_ptr, cursor);
    k_fill<<<EB, 256, 0, stream>>>(src, dst, cursor, csr_src);
    k_zinit<<<NB, 256, 0, stream>>>(emb, wsv, wdv, zs0, zd0);

    // layer 1: h_in = emb -> h1, compute zs1/zd1
    k_layer<false, true><<<NB, 256, 0, stream>>>(emb, emb, row_ptr, csr_src, zs0, zd0,
                                                 att_csr, h1, wsv, wdv, zs1, zd1);
    // layer 2: h_in = h1 -> out (final h), store att
    k_layer<true, false><<<NB, 256, 0, stream>>>(h1, emb, row_ptr, csr_src, zs1, zd1,
                                                 att_csr, out, wsv, wdv, zs0, zd0);

    k_loss<<<NB, 256, 0, stream>>>(out, emb, row_ptr, csr_src, att_csr, lossAcc);
    k_finalize<<<1, 1, 0, stream>>>(lossAcc, out + (size_t)NNODES * HDIM);
}

// Round 2
// 425.647 us; speedup vs baseline: 2.4933x; 2.4933x over previous
//
#include <hip/hip_runtime.h>

#define NNODES 50000
#define NEDGES 800000
#define HDIM 64
#define GAMMA 0.2f

__device__ __forceinline__ float wave_sum(float v) {
    #pragma unroll
    for (int off = 32; off; off >>= 1) v += __shfl_xor(v, off, 64);
    return v;
}
__device__ __forceinline__ float wave_max(float v) {
    #pragma unroll
    for (int off = 32; off; off >>= 1) v = fmaxf(v, __shfl_xor(v, off, 64));
    return v;
}
// reduce within each 16-lane group
__device__ __forceinline__ float group16_sum(float v) {
    v += __shfl_xor(v, 1, 64);
    v += __shfl_xor(v, 2, 64);
    v += __shfl_xor(v, 4, 64);
    v += __shfl_xor(v, 8, 64);
    return v;
}

// ws[k] = sum_j W_fc[j,k] * a_src[j] ; wd[k] = sum_j W_fc[j,k] * a_dst[j]
__global__ void k_wswd(const float* __restrict__ Wfc, const float* __restrict__ attn,
                       float* __restrict__ ws, float* __restrict__ wd) {
    int k = threadIdx.x; // 64 threads
    float s = 0.f, d = 0.f;
    for (int j = 0; j < HDIM; ++j) {
        float w = Wfc[j * HDIM + k];
        s += w * attn[j];
        d += w * attn[HDIM + j];
    }
    ws[k] = s; wd[k] = d;
}

// zs[n] = h[n]·ws, zd[n] = h[n]·wd  (wave per node)
__global__ __launch_bounds__(256) void k_zinit(const float* __restrict__ h,
                                               const float* __restrict__ ws,
                                               const float* __restrict__ wd,
                                               float* __restrict__ zs, float* __restrict__ zd) {
    int wid = (blockIdx.x * blockDim.x + threadIdx.x) >> 6;
    int lane = threadIdx.x & 63;
    if (wid >= NNODES) return;
    float v = h[wid * HDIM + lane];
    float a = wave_sum(v * ws[lane]);
    float b = wave_sum(v * wd[lane]);
    if (lane == 0) { zs[wid] = a; zd[wid] = b; }
}

__global__ __launch_bounds__(256) void k_count(const int* __restrict__ dst, int* __restrict__ deg) {
    int k = blockIdx.x * blockDim.x + threadIdx.x;
    if (k < NEDGES) atomicAdd(&deg[dst[k]], 1);
}

// single-block exclusive scan of deg -> row_ptr, cursor
__global__ __launch_bounds__(1024) void k_scan(const int* __restrict__ deg,
                                               int* __restrict__ row_ptr, int* __restrict__ cursor) {
    __shared__ int sums[1024];
    int t = threadIdx.x;
    const int per = (NNODES + 1023) / 1024;
    int lo = t * per, hi = min(lo + per, NNODES);
    int s = 0;
    for (int i = lo; i < hi; ++i) s += deg[i];
    sums[t] = s;
    __syncthreads();
    for (int off = 1; off < 1024; off <<= 1) {
        int v = (t >= off) ? sums[t - off] : 0;
        __syncthreads();
        sums[t] += v;
        __syncthreads();
    }
    int run = (t > 0) ? sums[t - 1] : 0;
    for (int i = lo; i < hi; ++i) {
        row_ptr[i] = run; cursor[i] = run;
        run += deg[i];
    }
    if (t == 0) row_ptr[NNODES] = NEDGES;
}

__global__ __launch_bounds__(256) void k_fill(const int* __restrict__ src, const int* __restrict__ dst,
                                              int* __restrict__ cursor, int* __restrict__ csr_src,
                                              int* __restrict__ csr_dst) {
    int k = blockIdx.x * blockDim.x + threadIdx.x;
    if (k >= NEDGES) return;
    int d = dst[k];
    int pos = atomicAdd(&cursor[d], 1);
    csr_src[pos] = src[k];
    csr_dst[pos] = d;
}

// One wave per node: segment softmax over incoming edges + crf gather + h update.
template <bool STORE_ATT, bool COMPUTE_Z>
__global__ __launch_bounds__(256) void k_layer(const float* __restrict__ h_in,
                                               const float* __restrict__ emb,
                                               const int* __restrict__ row_ptr,
                                               const int* __restrict__ csr_src,
                                               const float* __restrict__ zs,
                                               const float* __restrict__ zd,
                                               float* __restrict__ att_csr,
                                               float* __restrict__ h_out,
                                               const float* __restrict__ ws,
                                               const float* __restrict__ wd,
                                               float* __restrict__ zs_out,
                                               float* __restrict__ zd_out) {
    int wid = (blockIdx.x * blockDim.x + threadIdx.x) >> 6;
    int lane = threadIdx.x & 63;
    if (wid >= NNODES) return;
    int s0 = row_ptr[wid], s1 = row_ptr[wid + 1];
    float zdn = zd[wid];

    // phase 1: max of leaky(e)
    float m = -INFINITY;
    for (int base = s0; base < s1; base += 64) {
        int i = base + lane;
        if (i < s1) {
            int s = csr_src[i];
            float e = zs[s] + zdn;
            e = e > 0.f ? e : GAMMA * e;
            m = fmaxf(m, e);
        }
    }
    m = wave_max(m);
    // phase 2: denom
    float dsum = 0.f;
    for (int base = s0; base < s1; base += 64) {
        int i = base + lane;
        if (i < s1) {
            int s = csr_src[i];
            float e = zs[s] + zdn;
            e = e > 0.f ? e : GAMMA * e;
            dsum += __expf(e - m);
        }
    }
    dsum = wave_sum(dsum);
    float inv = 1.f / fmaxf(dsum, 1e-16f);

    // phase 3: crf accumulate, 4 edges per iteration, float4 rows
    const int sub = lane >> 4, q16 = lane & 15;
    float4 acc = make_float4(0.f, 0.f, 0.f, 0.f);
    for (int base = s0; base < s1; base += 64) {
        int i = base + lane;
        float ex = 0.f; int s = 0;
        if (i < s1) {
            s = csr_src[i];
            float e = zs[s] + zdn;
            e = e > 0.f ? e : GAMMA * e;
            ex = __expf(e - m);
            if (STORE_ATT) att_csr[i] = ex * inv;
        }
        int ne = min(64, s1 - base);
        for (int j = 0; j < ne; j += 4) {
            int jj = j + sub;                       // this sub-group's edge slot
            float w = __shfl(ex, jj, 64);           // 0 for jj >= ne (those lanes had ex=0,s=0)
            int sj = __shfl(s, jj, 64);
            const float4 row = *(const float4*)&h_in[(size_t)sj * HDIM + 4 * q16];
            acc.x += w * row.x; acc.y += w * row.y;
            acc.z += w * row.z; acc.w += w * row.w;
        }
    }
    // reduce partial sums across the 4 sub-groups (lanes xor 16, 32)
    #pragma unroll
    for (int off = 16; off <= 32; off <<= 1) {
        acc.x += __shfl_xor(acc.x, off, 64);
        acc.y += __shfl_xor(acc.y, off, 64);
        acc.z += __shfl_xor(acc.z, off, 64);
        acc.w += __shfl_xor(acc.w, off, 64);
    }
    const float4 ev = *(const float4*)&emb[(size_t)wid * HDIM + 4 * q16];
    float4 hv;
    hv.x = 0.5f * (ev.x + acc.x * inv);
    hv.y = 0.5f * (ev.y + acc.y * inv);
    hv.z = 0.5f * (ev.z + acc.z * inv);
    hv.w = 0.5f * (ev.w + acc.w * inv);
    if (sub == 0) *(float4*)&h_out[(size_t)wid * HDIM + 4 * q16] = hv;
    if (COMPUTE_Z) {
        float pa = 0.f, pb = 0.f;
        if (sub == 0) {
            const float4 w4 = *(const float4*)&ws[4 * q16];
            const float4 d4 = *(const float4*)&wd[4 * q16];
            pa = hv.x * w4.x + hv.y * w4.y + hv.z * w4.z + hv.w * w4.w;
            pb = hv.x * d4.x + hv.y * d4.y + hv.z * d4.z + hv.w * d4.w;
        }
        float a = wave_sum(pa);
        float b = wave_sum(pb);
        if (lane == 0) { zs_out[wid] = a; zd_out[wid] = b; }
    }
}

// Edge-parallel fused loss: loss_a over nodes + loss_b as a flat sum over edges.
// 4 items per wave (16 lanes x float4 each), per-lane accumulate, block reduce,
// one atomicAdd per block.
__global__ __launch_bounds__(256) void k_loss2(const float* __restrict__ h,
                                               const float* __restrict__ emb,
                                               const int* __restrict__ csr_src,
                                               const int* __restrict__ csr_dst,
                                               const float* __restrict__ att_csr,
                                               float* __restrict__ acc) {
    const int lane = threadIdx.x & 63;
    const int wib = threadIdx.x >> 6;
    const int gw = (blockIdx.x * blockDim.x + threadIdx.x) >> 6;
    const int nwaves = (gridDim.x * blockDim.x) >> 6;
    const int sub = lane >> 4, q16 = lane & 15;
    float lb = 0.f;

    // loss_a: nodes, 4 per wave
    for (int g = gw; g < NNODES / 4; g += nwaves) {
        int n = g * 4 + sub;
        const float4 hv = *(const float4*)&h[(size_t)n * HDIM + 4 * q16];
        const float4 ev = *(const float4*)&emb[(size_t)n * HDIM + 4 * q16];
        float dx = hv.x - ev.x, dy = hv.y - ev.y, dz = hv.z - ev.z, dw = hv.w - ev.w;
        float ss = group16_sum(dx * dx + dy * dy + dz * dz + dw * dw);
        if (q16 == 0) lb += 0.5f * ss;
    }
    // loss_b: edges, 4 per wave
    for (int g = gw; g < NEDGES / 4; g += nwaves) {
        int e = g * 4 + sub;
        int s = csr_src[e], d = csr_dst[e];
        const float4 hs = *(const float4*)&h[(size_t)s * HDIM + 4 * q16];
        const float4 hd = *(const float4*)&h[(size_t)d * HDIM + 4 * q16];
        float dx = hd.x - hs.x, dy = hd.y - hs.y, dz = hd.z - hs.z, dw = hd.w - hs.w;
        float ss = group16_sum(dx * dx + dy * dy + dz * dz + dw * dw);
        if (q16 == 0) lb += 0.5f * att_csr[e] * sqrtf(ss + 1e-12f);
    }
    lb = wave_sum(lb);
    __shared__ float part[4];
    if (lane == 0) part[wib] = lb;
    __syncthreads();
    if (threadIdx.x == 0)
        atomicAdd(acc, part[0] + part[1] + part[2] + part[3]);
}

__global__ void k_finalize(const float* __restrict__ acc, float* __restrict__ out_loss) {
    out_loss[0] = acc[0] / (float)NNODES;
}

extern "C" void kernel_launch(void* const* d_in, const int* in_sizes, int n_in,
                              void* d_out, int out_size, void* d_ws, size_t ws_size,
                              hipStream_t stream) {
    const float* emb  = (const float*)d_in[0];
    const float* Wfc  = (const float*)d_in[1];
    const float* attn = (const float*)d_in[2];
    const int*   src  = (const int*)d_in[3];
    const int*   dst  = (const int*)d_in[4];
    float* out = (float*)d_out; // [N*H] h, then [1] loss

    char* p = (char*)d_ws;
    int*   deg     = (int*)p;   p += (size_t)NNODES * 4;
    int*   cursor  = (int*)p;   p += (size_t)NNODES * 4;
    int*   row_ptr = (int*)p;   p += (size_t)(NNODES + 1) * 4;
    p = (char*)(((size_t)p + 255) & ~(size_t)255);
    int*   csr_src = (int*)p;   p += (size_t)NEDGES * 4;
    int*   csr_dst = (int*)p;   p += (size_t)NEDGES * 4;
    float* att_csr = (float*)p; p += (size_t)NEDGES * 4;
    float* zs0     = (float*)p; p += (size_t)NNODES * 4;
    float* zd0     = (float*)p; p += (size_t)NNODES * 4;
    float* zs1     = (float*)p; p += (size_t)NNODES * 4;
    float* zd1     = (float*)p; p += (size_t)NNODES * 4;
    float* wsv     = (float*)p; p += 64 * 4;
    float* wdv     = (float*)p; p += 64 * 4;
    float* lossAcc = (float*)p; p += 256;
    p = (char*)(((size_t)p + 255) & ~(size_t)255);
    float* h1      = (float*)p; p += (size_t)NNODES * HDIM * 4;

    hipMemsetAsync(deg, 0, (size_t)NNODES * 4, stream);
    hipMemsetAsync(lossAcc, 0, 4, stream);

    const int EB = (NEDGES + 255) / 256;
    const int NB = (NNODES + 3) / 4;   // 4 waves/block, 1 node per wave

    k_wswd<<<1, 64, 0, stream>>>(Wfc, attn, wsv, wdv);
    k_count<<<EB, 256, 0, stream>>>(dst, deg);
    k_scan<<<1, 1024, 0, stream>>>(deg, row_ptr, cursor);
    k_fill<<<EB, 256, 0, stream>>>(src, dst, cursor, csr_src, csr_dst);
    k_zinit<<<NB, 256, 0, stream>>>(emb, wsv, wdv, zs0, zd0);

    // layer 1: h_in = emb -> h1, compute zs1/zd1
    k_layer<false, true><<<NB, 256, 0, stream>>>(emb, emb, row_ptr, csr_src, zs0, zd0,
                                                 att_csr, h1, wsv, wdv, zs1, zd1);
    // layer 2: h_in = h1 -> out (final h), store att
    k_layer<true, false><<<NB, 256, 0, stream>>>(h1, emb, row_ptr, csr_src, zs1, zd1,
                                                 att_csr, out, wsv, wdv, zs0, zd0);

    k_loss2<<<2048, 256, 0, stream>>>(out, emb, csr_src, csr_dst, att_csr, lossAcc);
    k_finalize<<<1, 1, 0, stream>>>(lossAcc, out + (size_t)NNODES * HDIM);
}

// Round 3
// 327.772 us; speedup vs baseline: 3.2378x; 1.2986x over previous
//
#include <hip/hip_runtime.h>

#define NNODES 50000
#define NEDGES 800000
#define HDIM 64
#define GAMMA 0.2f
#define SCAN_B 256
#define SCAN_NB ((NNODES + SCAN_B - 1) / SCAN_B)   // 196

__device__ __forceinline__ float wave_sum(float v) {
    #pragma unroll
    for (int off = 32; off; off >>= 1) v += __shfl_xor(v, off, 64);
    return v;
}
__device__ __forceinline__ float wave_max(float v) {
    #pragma unroll
    for (int off = 32; off; off >>= 1) v = fmaxf(v, __shfl_xor(v, off, 64));
    return v;
}
__device__ __forceinline__ int wave_sum_i(int v) {
    #pragma unroll
    for (int off = 32; off; off >>= 1) v += __shfl_xor(v, off, 64);
    return v;
}
// reduce within each 16-lane group
__device__ __forceinline__ float group16_sum(float v) {
    v += __shfl_xor(v, 1, 64);
    v += __shfl_xor(v, 2, 64);
    v += __shfl_xor(v, 4, 64);
    v += __shfl_xor(v, 8, 64);
    return v;
}

// ws[k] = sum_j W_fc[j,k] * a_src[j] ; wd[k] = sum_j W_fc[j,k] * a_dst[j]
__global__ void k_wswd(const float* __restrict__ Wfc, const float* __restrict__ attn,
                       float* __restrict__ ws, float* __restrict__ wd) {
    int k = threadIdx.x; // 64 threads
    float s = 0.f, d = 0.f;
    for (int j = 0; j < HDIM; ++j) {
        float w = Wfc[j * HDIM + k];
        s += w * attn[j];
        d += w * attn[HDIM + j];
    }
    ws[k] = s; wd[k] = d;
}

// zs[n] = h[n]·ws, zd[n] = h[n]·wd  (wave per node)
__global__ __launch_bounds__(256) void k_zinit(const float* __restrict__ h,
                                               const float* __restrict__ ws,
                                               const float* __restrict__ wd,
                                               float* __restrict__ zs, float* __restrict__ zd) {
    int wid = (blockIdx.x * blockDim.x + threadIdx.x) >> 6;
    int lane = threadIdx.x & 63;
    if (wid >= NNODES) return;
    float v = h[wid * HDIM + lane];
    float a = wave_sum(v * ws[lane]);
    float b = wave_sum(v * wd[lane]);
    if (lane == 0) { zs[wid] = a; zd[wid] = b; }
}

__global__ __launch_bounds__(256) void k_count(const int* __restrict__ dst, int* __restrict__ deg) {
    int k = blockIdx.x * blockDim.x + threadIdx.x;
    if (k < NEDGES) atomicAdd(&deg[dst[k]], 1);
}

// --- hierarchical scan: deg -> row_ptr (exclusive), cursor ---
__global__ __launch_bounds__(SCAN_B) void k_scan1(const int* __restrict__ deg,
                                                  int* __restrict__ blockSums) {
    int t = threadIdx.x;
    int idx = blockIdx.x * SCAN_B + t;
    int v = (idx < NNODES) ? deg[idx] : 0;
    int ws = wave_sum_i(v);
    __shared__ int part[4];
    if ((t & 63) == 0) part[t >> 6] = ws;
    __syncthreads();
    if (t == 0) blockSums[blockIdx.x] = part[0] + part[1] + part[2] + part[3];
}

__global__ __launch_bounds__(SCAN_B) void k_scan2(int* __restrict__ blockSums,
                                                  int* __restrict__ blockOffs) {
    __shared__ int s[SCAN_B];
    int t = threadIdx.x;
    int v = (t < SCAN_NB) ? blockSums[t] : 0;
    s[t] = v;
    __syncthreads();
    for (int off = 1; off < SCAN_B; off <<= 1) {
        int x = (t >= off) ? s[t - off] : 0;
        __syncthreads();
        s[t] += x;
        __syncthreads();
    }
    if (t < SCAN_NB) blockOffs[t] = s[t] - v;   // exclusive
}

__global__ __launch_bounds__(SCAN_B) void k_scan3(const int* __restrict__ deg,
                                                  const int* __restrict__ blockOffs,
                                                  int* __restrict__ row_ptr,
                                                  int* __restrict__ cursor) {
    __shared__ int s[SCAN_B];
    int t = threadIdx.x;
    int idx = blockIdx.x * SCAN_B + t;
    int v = (idx < NNODES) ? deg[idx] : 0;
    s[t] = v;
    __syncthreads();
    for (int off = 1; off < SCAN_B; off <<= 1) {
        int x = (t >= off) ? s[t - off] : 0;
        __syncthreads();
        s[t] += x;
        __syncthreads();
    }
    if (idx < NNODES) {
        int excl = s[t] - v + blockOffs[blockIdx.x];
        row_ptr[idx] = excl;
        cursor[idx] = excl;
    }
    if (idx == 0) row_ptr[NNODES] = NEDGES;
}

__global__ __launch_bounds__(256) void k_fill(const int* __restrict__ src, const int* __restrict__ dst,
                                              int* __restrict__ cursor, int* __restrict__ csr_src,
                                              int* __restrict__ csr_dst) {
    int k = blockIdx.x * blockDim.x + threadIdx.x;
    if (k >= NEDGES) return;
    int d = dst[k];
    int pos = atomicAdd(&cursor[d], 1);
    csr_src[pos] = src[k];
    csr_dst[pos] = d;
}

// One wave per node: segment softmax over incoming edges + crf gather + h update.
template <bool STORE_ATT, bool COMPUTE_Z>
__global__ __launch_bounds__(256) void k_layer(const float* __restrict__ h_in,
                                               const float* __restrict__ emb,
                                               const int* __restrict__ row_ptr,
                                               const int* __restrict__ csr_src,
                                               const float* __restrict__ zs,
                                               const float* __restrict__ zd,
                                               float* __restrict__ att_csr,
                                               float* __restrict__ h_out,
                                               const float* __restrict__ ws,
                                               const float* __restrict__ wd,
                                               float* __restrict__ zs_out,
                                               float* __restrict__ zd_out) {
    int wid = (blockIdx.x * blockDim.x + threadIdx.x) >> 6;
    int lane = threadIdx.x & 63;
    if (wid >= NNODES) return;
    int s0 = row_ptr[wid], s1 = row_ptr[wid + 1];
    float zdn = zd[wid];

    // phase 1: max of leaky(e)
    float m = -INFINITY;
    for (int base = s0; base < s1; base += 64) {
        int i = base + lane;
        if (i < s1) {
            int s = csr_src[i];
            float e = zs[s] + zdn;
            e = e > 0.f ? e : GAMMA * e;
            m = fmaxf(m, e);
        }
    }
    m = wave_max(m);
    // phase 2: denom
    float dsum = 0.f;
    for (int base = s0; base < s1; base += 64) {
        int i = base + lane;
        if (i < s1) {
            int s = csr_src[i];
            float e = zs[s] + zdn;
            e = e > 0.f ? e : GAMMA * e;
            dsum += __expf(e - m);
        }
    }
    dsum = wave_sum(dsum);
    float inv = 1.f / fmaxf(dsum, 1e-16f);

    // phase 3: crf accumulate, 4 edges per iteration, float4 rows
    const int sub = lane >> 4, q16 = lane & 15;
    float4 acc = make_float4(0.f, 0.f, 0.f, 0.f);
    for (int base = s0; base < s1; base += 64) {
        int i = base + lane;
        float ex = 0.f; int s = 0;
        if (i < s1) {
            s = csr_src[i];
            float e = zs[s] + zdn;
            e = e > 0.f ? e : GAMMA * e;
            ex = __expf(e - m);
            if (STORE_ATT) att_csr[i] = ex * inv;
        }
        int ne = min(64, s1 - base);
        for (int j = 0; j < ne; j += 4) {
            int jj = j + sub;                       // this sub-group's edge slot
            float w = __shfl(ex, jj, 64);           // 0 for jj >= ne (those lanes had ex=0,s=0)
            int sj = __shfl(s, jj, 64);
            const float4 row = *(const float4*)&h_in[(size_t)sj * HDIM + 4 * q16];
            acc.x += w * row.x; acc.y += w * row.y;
            acc.z += w * row.z; acc.w += w * row.w;
        }
    }
    // reduce partial sums across the 4 sub-groups (lanes xor 16, 32)
    #pragma unroll
    for (int off = 16; off <= 32; off <<= 1) {
        acc.x += __shfl_xor(acc.x, off, 64);
        acc.y += __shfl_xor(acc.y, off, 64);
        acc.z += __shfl_xor(acc.z, off, 64);
        acc.w += __shfl_xor(acc.w, off, 64);
    }
    const float4 ev = *(const float4*)&emb[(size_t)wid * HDIM + 4 * q16];
    float4 hv;
    hv.x = 0.5f * (ev.x + acc.x * inv);
    hv.y = 0.5f * (ev.y + acc.y * inv);
    hv.z = 0.5f * (ev.z + acc.z * inv);
    hv.w = 0.5f * (ev.w + acc.w * inv);
    if (sub == 0) *(float4*)&h_out[(size_t)wid * HDIM + 4 * q16] = hv;
    if (COMPUTE_Z) {
        float pa = 0.f, pb = 0.f;
        if (sub == 0) {
            const float4 w4 = *(const float4*)&ws[4 * q16];
            const float4 d4 = *(const float4*)&wd[4 * q16];
            pa = hv.x * w4.x + hv.y * w4.y + hv.z * w4.z + hv.w * w4.w;
            pb = hv.x * d4.x + hv.y * d4.y + hv.z * d4.z + hv.w * d4.w;
        }
        float a = wave_sum(pa);
        float b = wave_sum(pb);
        if (lane == 0) { zs_out[wid] = a; zd_out[wid] = b; }
    }
}

// Edge-parallel fused loss: loss_a over nodes + loss_b as a flat sum over edges.
__global__ __launch_bounds__(256) void k_loss2(const float* __restrict__ h,
                                               const float* __restrict__ emb,
                                               const int* __restrict__ csr_src,
                                               const int* __restrict__ csr_dst,
                                               const float* __restrict__ att_csr,
                                               float* __restrict__ acc) {
    const int lane = threadIdx.x & 63;
    const int wib = threadIdx.x >> 6;
    const int gw = (blockIdx.x * blockDim.x + threadIdx.x) >> 6;
    const int nwaves = (gridDim.x * blockDim.x) >> 6;
    const int sub = lane >> 4, q16 = lane & 15;
    float lb = 0.f;

    // loss_a: nodes, 4 per wave
    for (int g = gw; g < NNODES / 4; g += nwaves) {
        int n = g * 4 + sub;
        const float4 hv = *(const float4*)&h[(size_t)n * HDIM + 4 * q16];
        const float4 ev = *(const float4*)&emb[(size_t)n * HDIM + 4 * q16];
        float dx = hv.x - ev.x, dy = hv.y - ev.y, dz = hv.z - ev.z, dw = hv.w - ev.w;
        float ss = group16_sum(dx * dx + dy * dy + dz * dz + dw * dw);
        if (q16 == 0) lb += 0.5f * ss;
    }
    // loss_b: edges, 4 per wave
    for (int g = gw; g < NEDGES / 4; g += nwaves) {
        int e = g * 4 + sub;
        int s = csr_src[e], d = csr_dst[e];
        const float4 hs = *(const float4*)&h[(size_t)s * HDIM + 4 * q16];
        const float4 hd = *(const float4*)&h[(size_t)d * HDIM + 4 * q16];
        float dx = hd.x - hs.x, dy = hd.y - hs.y, dz = hd.z - hs.z, dw = hd.w - hs.w;
        float ss = group16_sum(dx * dx + dy * dy + dz * dz + dw * dw);
        if (q16 == 0) lb += 0.5f * att_csr[e] * sqrtf(ss + 1e-12f);
    }
    lb = wave_sum(lb);
    __shared__ float part[4];
    if (lane == 0) part[wib] = lb;
    __syncthreads();
    if (threadIdx.x == 0)
        atomicAdd(acc, part[0] + part[1] + part[2] + part[3]);
}

__global__ void k_finalize(const float* __restrict__ acc, float* __restrict__ out_loss) {
    out_loss[0] = acc[0] / (float)NNODES;
}

extern "C" void kernel_launch(void* const* d_in, const int* in_sizes, int n_in,
                              void* d_out, int out_size, void* d_ws, size_t ws_size,
                              hipStream_t stream) {
    const float* emb  = (const float*)d_in[0];
    const float* Wfc  = (const float*)d_in[1];
    const float* attn = (const float*)d_in[2];
    const int*   src  = (const int*)d_in[3];
    const int*   dst  = (const int*)d_in[4];
    float* out = (float*)d_out; // [N*H] h, then [1] loss

    char* p = (char*)d_ws;
    int*   deg     = (int*)p;   p += (size_t)NNODES * 4;
    int*   cursor  = (int*)p;   p += (size_t)NNODES * 4;
    int*   row_ptr = (int*)p;   p += (size_t)(NNODES + 1) * 4;
    int*   bsums   = (int*)p;   p += (size_t)SCAN_NB * 4;
    int*   boffs   = (int*)p;   p += (size_t)SCAN_NB * 4;
    p = (char*)(((size_t)p + 255) & ~(size_t)255);
    int*   csr_src = (int*)p;   p += (size_t)NEDGES * 4;
    int*   csr_dst = (int*)p;   p += (size_t)NEDGES * 4;
    float* att_csr = (float*)p; p += (size_t)NEDGES * 4;
    float* zs0     = (float*)p; p += (size_t)NNODES * 4;
    float* zd0     = (float*)p; p += (size_t)NNODES * 4;
    float* zs1     = (float*)p; p += (size_t)NNODES * 4;
    float* zd1     = (float*)p; p += (size_t)NNODES * 4;
    float* wsv     = (float*)p; p += 64 * 4;
    float* wdv     = (float*)p; p += 64 * 4;
    float* lossAcc = (float*)p; p += 256;
    p = (char*)(((size_t)p + 255) & ~(size_t)255);
    float* h1      = (float*)p; p += (size_t)NNODES * HDIM * 4;

    hipMemsetAsync(deg, 0, (size_t)NNODES * 4, stream);
    hipMemsetAsync(lossAcc, 0, 4, stream);

    const int EB = (NEDGES + 255) / 256;
    const int NB = (NNODES + 3) / 4;   // 4 waves/block, 1 node per wave

    k_wswd<<<1, 64, 0, stream>>>(Wfc, attn, wsv, wdv);
    k_count<<<EB, 256, 0, stream>>>(dst, deg);
    k_scan1<<<SCAN_NB, SCAN_B, 0, stream>>>(deg, bsums);
    k_scan2<<<1, SCAN_B, 0, stream>>>(bsums, boffs);
    k_scan3<<<SCAN_NB, SCAN_B, 0, stream>>>(deg, boffs, row_ptr, cursor);
    k_fill<<<EB, 256, 0, stream>>>(src, dst, cursor, csr_src, csr_dst);
    k_zinit<<<NB, 256, 0, stream>>>(emb, wsv, wdv, zs0, zd0);

    // layer 1: h_in = emb -> h1, compute zs1/zd1
    k_layer<false, true><<<NB, 256, 0, stream>>>(emb, emb, row_ptr, csr_src, zs0, zd0,
                                                 att_csr, h1, wsv, wdv, zs1, zd1);
    // layer 2: h_in = h1 -> out (final h), store att
    k_layer<true, false><<<NB, 256, 0, stream>>>(h1, emb, row_ptr, csr_src, zs1, zd1,
                                                 att_csr, out, wsv, wdv, zs0, zd0);

    k_loss2<<<2048, 256, 0, stream>>>(out, emb, csr_src, csr_dst, att_csr, lossAcc);
    k_finalize<<<1, 1, 0, stream>>>(lossAcc, out + (size_t)NNODES * HDIM);
}

// Round 4
// 302.894 us; speedup vs baseline: 3.5037x; 1.0821x over previous
//
#include <hip/hip_runtime.h>

#define NNODES 50000
#define NEDGES 800000
#define HDIM 64
#define GAMMA 0.2f
#define SCAN_B 256
#define SCAN_NB ((NNODES + SCAN_B - 1) / SCAN_B)   // 196

__device__ __forceinline__ float wave_sum(float v) {
    #pragma unroll
    for (int off = 32; off; off >>= 1) v += __shfl_xor(v, off, 64);
    return v;
}
__device__ __forceinline__ float wave_max(float v) {
    #pragma unroll
    for (int off = 32; off; off >>= 1) v = fmaxf(v, __shfl_xor(v, off, 64));
    return v;
}
__device__ __forceinline__ int wave_sum_i(int v) {
    #pragma unroll
    for (int off = 32; off; off >>= 1) v += __shfl_xor(v, off, 64);
    return v;
}
__device__ __forceinline__ float group16_sum(float v) {
    v += __shfl_xor(v, 1, 64);
    v += __shfl_xor(v, 2, 64);
    v += __shfl_xor(v, 4, 64);
    v += __shfl_xor(v, 8, 64);
    return v;
}

// zs[n] = h[n]·ws, zd[n] = h[n]·wd  (wave per node)
__global__ __launch_bounds__(256) void k_zinit(const float* __restrict__ h,
                                               const float* __restrict__ ws,
                                               const float* __restrict__ wd,
                                               float* __restrict__ zs, float* __restrict__ zd) {
    int wid = (blockIdx.x * blockDim.x + threadIdx.x) >> 6;
    int lane = threadIdx.x & 63;
    if (wid >= NNODES) return;
    float v = h[wid * HDIM + lane];
    float a = wave_sum(v * ws[lane]);
    float b = wave_sum(v * wd[lane]);
    if (lane == 0) { zs[wid] = a; zd[wid] = b; }
}

// 4 edges per thread via int4
__global__ __launch_bounds__(256) void k_count(const int4* __restrict__ dst4, int* __restrict__ deg) {
    int k = blockIdx.x * blockDim.x + threadIdx.x;
    if (k >= NEDGES / 4) return;
    int4 d = dst4[k];
    atomicAdd(&deg[d.x], 1);
    atomicAdd(&deg[d.y], 1);
    atomicAdd(&deg[d.z], 1);
    atomicAdd(&deg[d.w], 1);
}

// --- hierarchical scan: deg -> row_ptr (exclusive), cursor ---
__global__ __launch_bounds__(SCAN_B) void k_scan1(const int* __restrict__ deg,
                                                  int* __restrict__ blockSums) {
    int t = threadIdx.x;
    int idx = blockIdx.x * SCAN_B + t;
    int v = (idx < NNODES) ? deg[idx] : 0;
    int ws = wave_sum_i(v);
    __shared__ int part[4];
    if ((t & 63) == 0) part[t >> 6] = ws;
    __syncthreads();
    if (t == 0) blockSums[blockIdx.x] = part[0] + part[1] + part[2] + part[3];
}

// scan of block sums + (fused) ws/wd precompute: ws[k]=sum_j Wfc[j,k]*a_src[j]
__global__ __launch_bounds__(SCAN_B) void k_scan2(int* __restrict__ blockSums,
                                                  int* __restrict__ blockOffs,
                                                  const float* __restrict__ Wfc,
                                                  const float* __restrict__ attn,
                                                  float* __restrict__ wsv,
                                                  float* __restrict__ wdv) {
    int t = threadIdx.x;
    if (t < 128) {
        int k = t & 63;
        const float* av = attn + ((t >= 64) ? HDIM : 0);
        float s = 0.f;
        for (int j = 0; j < HDIM; ++j) s += Wfc[j * HDIM + k] * av[j];
        if (t < 64) wsv[k] = s; else wdv[k] = s;
    }
    __shared__ int s[SCAN_B];
    int v = (t < SCAN_NB) ? blockSums[t] : 0;
    s[t] = v;
    __syncthreads();
    for (int off = 1; off < SCAN_B; off <<= 1) {
        int x = (t >= off) ? s[t - off] : 0;
        __syncthreads();
        s[t] += x;
        __syncthreads();
    }
    if (t < SCAN_NB) blockOffs[t] = s[t] - v;   // exclusive
}

__global__ __launch_bounds__(SCAN_B) void k_scan3(const int* __restrict__ deg,
                                                  const int* __restrict__ blockOffs,
                                                  int* __restrict__ row_ptr,
                                                  int* __restrict__ cursor) {
    __shared__ int s[SCAN_B];
    int t = threadIdx.x;
    int idx = blockIdx.x * SCAN_B + t;
    int v = (idx < NNODES) ? deg[idx] : 0;
    s[t] = v;
    __syncthreads();
    for (int off = 1; off < SCAN_B; off <<= 1) {
        int x = (t >= off) ? s[t - off] : 0;
        __syncthreads();
        s[t] += x;
        __syncthreads();
    }
    if (idx < NNODES) {
        int excl = s[t] - v + blockOffs[blockIdx.x];
        row_ptr[idx] = excl;
        cursor[idx] = excl;
    }
    if (idx == 0) row_ptr[NNODES] = NEDGES;
}

// 4 edges per thread; packed (src,dst) int2 single 8B scattered store
__global__ __launch_bounds__(256) void k_fill(const int4* __restrict__ src4,
                                              const int4* __restrict__ dst4,
                                              int* __restrict__ cursor, int2* __restrict__ csr) {
    int k = blockIdx.x * blockDim.x + threadIdx.x;
    if (k >= NEDGES / 4) return;
    int4 s = src4[k];
    int4 d = dst4[k];
    int p0 = atomicAdd(&cursor[d.x], 1); csr[p0] = make_int2(s.x, d.x);
    int p1 = atomicAdd(&cursor[d.y], 1); csr[p1] = make_int2(s.y, d.y);
    int p2 = atomicAdd(&cursor[d.z], 1); csr[p2] = make_int2(s.z, d.z);
    int p3 = atomicAdd(&cursor[d.w], 1); csr[p3] = make_int2(s.w, d.w);
}

// One wave per node; single-pass register-resident softmax for deg<=64,
// unrolled gather with 4 row loads in flight.
template <bool STORE_ATT, bool COMPUTE_Z>
__global__ __launch_bounds__(256) void k_layer(const float* __restrict__ h_in,
                                               const float* __restrict__ emb,
                                               const int* __restrict__ row_ptr,
                                               const int2* __restrict__ csr,
                                               const float* __restrict__ zs,
                                               const float* __restrict__ zd,
                                               float* __restrict__ att_csr,
                                               float* __restrict__ h_out,
                                               const float* __restrict__ ws,
                                               const float* __restrict__ wd,
                                               float* __restrict__ zs_out,
                                               float* __restrict__ zd_out) {
    int wid = (blockIdx.x * blockDim.x + threadIdx.x) >> 6;
    int lane = threadIdx.x & 63;
    if (wid >= NNODES) return;
    int s0 = row_ptr[wid], s1 = row_ptr[wid + 1];
    int ne = s1 - s0;
    float zdn = zd[wid];
    const int sub = lane >> 4, q16 = lane & 15;
    float4 acc = make_float4(0.f, 0.f, 0.f, 0.f);
    float inv;

    if (ne <= 64) {
        // ---- fast path: everything register-resident ----
        int s = 0; float e = -INFINITY;
        bool valid = lane < ne;
        if (valid) {
            s = csr[s0 + lane].x;
            float z = zs[s] + zdn;
            e = z > 0.f ? z : GAMMA * z;
        }
        float m = wave_max(e);
        float ex = valid ? __expf(e - m) : 0.f;
        float dsum = wave_sum(ex);
        inv = 1.f / fmaxf(dsum, 1e-16f);
        if (STORE_ATT && valid) att_csr[s0 + lane] = ex * inv;
        for (int j = 0; j < ne; j += 16) {
            int j0 = j + sub, j1 = j + 4 + sub, j2 = j + 8 + sub, j3 = j + 12 + sub;
            float w0 = __shfl(ex, j0, 64), w1 = __shfl(ex, j1, 64);
            float w2 = __shfl(ex, j2, 64), w3 = __shfl(ex, j3, 64);
            int t0 = __shfl(s, j0, 64), t1 = __shfl(s, j1, 64);
            int t2 = __shfl(s, j2, 64), t3 = __shfl(s, j3, 64);
            const float4 r0 = *(const float4*)&h_in[(size_t)t0 * HDIM + 4 * q16];
            const float4 r1 = *(const float4*)&h_in[(size_t)t1 * HDIM + 4 * q16];
            const float4 r2 = *(const float4*)&h_in[(size_t)t2 * HDIM + 4 * q16];
            const float4 r3 = *(const float4*)&h_in[(size_t)t3 * HDIM + 4 * q16];
            acc.x += w0 * r0.x + w1 * r1.x + w2 * r2.x + w3 * r3.x;
            acc.y += w0 * r0.y + w1 * r1.y + w2 * r2.y + w3 * r3.y;
            acc.z += w0 * r0.z + w1 * r1.z + w2 * r2.z + w3 * r3.z;
            acc.w += w0 * r0.w + w1 * r1.w + w2 * r2.w + w3 * r3.w;
        }
    } else {
        // ---- generic 3-phase path (deg > 64; statistically never here) ----
        float m = -INFINITY;
        for (int base = s0; base < s1; base += 64) {
            int i = base + lane;
            if (i < s1) {
                int s = csr[i].x;
                float z = zs[s] + zdn;
                z = z > 0.f ? z : GAMMA * z;
                m = fmaxf(m, z);
            }
        }
        m = wave_max(m);
        float dsum = 0.f;
        for (int base = s0; base < s1; base += 64) {
            int i = base + lane;
            if (i < s1) {
                int s = csr[i].x;
                float z = zs[s] + zdn;
                z = z > 0.f ? z : GAMMA * z;
                dsum += __expf(z - m);
            }
        }
        dsum = wave_sum(dsum);
        inv = 1.f / fmaxf(dsum, 1e-16f);
        for (int base = s0; base < s1; base += 64) {
            int i = base + lane;
            float ex = 0.f; int s = 0;
            if (i < s1) {
                s = csr[i].x;
                float z = zs[s] + zdn;
                z = z > 0.f ? z : GAMMA * z;
                ex = __expf(z - m);
                if (STORE_ATT) att_csr[i] = ex * inv;
            }
            int nc = min(64, s1 - base);
            for (int j = 0; j < nc; j += 16) {
                int j0 = j + sub, j1 = j + 4 + sub, j2 = j + 8 + sub, j3 = j + 12 + sub;
                float w0 = __shfl(ex, j0, 64), w1 = __shfl(ex, j1, 64);
                float w2 = __shfl(ex, j2, 64), w3 = __shfl(ex, j3, 64);
                int t0 = __shfl(s, j0, 64), t1 = __shfl(s, j1, 64);
                int t2 = __shfl(s, j2, 64), t3 = __shfl(s, j3, 64);
                const float4 r0 = *(const float4*)&h_in[(size_t)t0 * HDIM + 4 * q16];
                const float4 r1 = *(const float4*)&h_in[(size_t)t1 * HDIM + 4 * q16];
                const float4 r2 = *(const float4*)&h_in[(size_t)t2 * HDIM + 4 * q16];
                const float4 r3 = *(const float4*)&h_in[(size_t)t3 * HDIM + 4 * q16];
                acc.x += w0 * r0.x + w1 * r1.x + w2 * r2.x + w3 * r3.x;
                acc.y += w0 * r0.y + w1 * r1.y + w2 * r2.y + w3 * r3.y;
                acc.z += w0 * r0.z + w1 * r1.z + w2 * r2.z + w3 * r3.z;
                acc.w += w0 * r0.w + w1 * r1.w + w2 * r2.w + w3 * r3.w;
            }
        }
    }
    // reduce partial sums across the 4 sub-groups
    #pragma unroll
    for (int off = 16; off <= 32; off <<= 1) {
        acc.x += __shfl_xor(acc.x, off, 64);
        acc.y += __shfl_xor(acc.y, off, 64);
        acc.z += __shfl_xor(acc.z, off, 64);
        acc.w += __shfl_xor(acc.w, off, 64);
    }
    const float4 ev = *(const float4*)&emb[(size_t)wid * HDIM + 4 * q16];
    float4 hv;
    hv.x = 0.5f * (ev.x + acc.x * inv);
    hv.y = 0.5f * (ev.y + acc.y * inv);
    hv.z = 0.5f * (ev.z + acc.z * inv);
    hv.w = 0.5f * (ev.w + acc.w * inv);
    if (sub == 0) *(float4*)&h_out[(size_t)wid * HDIM + 4 * q16] = hv;
    if (COMPUTE_Z) {
        float pa = 0.f, pb = 0.f;
        if (sub == 0) {
            const float4 w4 = *(const float4*)&ws[4 * q16];
            const float4 d4 = *(const float4*)&wd[4 * q16];
            pa = hv.x * w4.x + hv.y * w4.y + hv.z * w4.z + hv.w * w4.w;
            pb = hv.x * d4.x + hv.y * d4.y + hv.z * d4.z + hv.w * d4.w;
        }
        float a = wave_sum(pa);
        float b = wave_sum(pb);
        if (lane == 0) { zs_out[wid] = a; zd_out[wid] = b; }
    }
}

// Edge-parallel fused loss, 2x unrolled (8 edges/wave/iter -> 4 gathers in flight per group)
__global__ __launch_bounds__(256) void k_loss2(const float* __restrict__ h,
                                               const float* __restrict__ emb,
                                               const int2* __restrict__ csr,
                                               const float* __restrict__ att_csr,
                                               float* __restrict__ acc) {
    const int lane = threadIdx.x & 63;
    const int wib = threadIdx.x >> 6;
    const int gw = (blockIdx.x * blockDim.x + threadIdx.x) >> 6;
    const int nwaves = (gridDim.x * blockDim.x) >> 6;
    const int sub = lane >> 4, q16 = lane & 15;
    float lb = 0.f;

    // loss_a: nodes, 4 per wave
    for (int g = gw; g < NNODES / 4; g += nwaves) {
        int n = g * 4 + sub;
        const float4 hv = *(const float4*)&h[(size_t)n * HDIM + 4 * q16];
        const float4 ev = *(const float4*)&emb[(size_t)n * HDIM + 4 * q16];
        float dx = hv.x - ev.x, dy = hv.y - ev.y, dz = hv.z - ev.z, dw = hv.w - ev.w;
        float ss = group16_sum(dx * dx + dy * dy + dz * dz + dw * dw);
        if (q16 == 0) lb += 0.5f * ss;
    }
    // loss_b: edges, 8 per wave (2 per 16-lane group)
    for (int g = gw; g < NEDGES / 8; g += nwaves) {
        int e0 = g * 8 + sub;
        int e1 = e0 + 4;
        int2 sd0 = csr[e0];
        int2 sd1 = csr[e1];
        const float4 hs0 = *(const float4*)&h[(size_t)sd0.x * HDIM + 4 * q16];
        const float4 hd0 = *(const float4*)&h[(size_t)sd0.y * HDIM + 4 * q16];
        const float4 hs1 = *(const float4*)&h[(size_t)sd1.x * HDIM + 4 * q16];
        const float4 hd1 = *(const float4*)&h[(size_t)sd1.y * HDIM + 4 * q16];
        float ax = hd0.x - hs0.x, ay = hd0.y - hs0.y, az = hd0.z - hs0.z, aw = hd0.w - hs0.w;
        float bx = hd1.x - hs1.x, by = hd1.y - hs1.y, bz = hd1.z - hs1.z, bw = hd1.w - hs1.w;
        float ss0 = group16_sum(ax * ax + ay * ay + az * az + aw * aw);
        float ss1 = group16_sum(bx * bx + by * by + bz * bz + bw * bw);
        if (q16 == 0)
            lb += 0.5f * (att_csr[e0] * sqrtf(ss0 + 1e-12f) +
                          att_csr[e1] * sqrtf(ss1 + 1e-12f));
    }
    lb = wave_sum(lb);
    __shared__ float part[4];
    if (lane == 0) part[wib] = lb;
    __syncthreads();
    if (threadIdx.x == 0)
        atomicAdd(acc, part[0] + part[1] + part[2] + part[3]);
}

__global__ void k_finalize(const float* __restrict__ acc, float* __restrict__ out_loss) {
    out_loss[0] = acc[0] / (float)NNODES;
}

extern "C" void kernel_launch(void* const* d_in, const int* in_sizes, int n_in,
                              void* d_out, int out_size, void* d_ws, size_t ws_size,
                              hipStream_t stream) {
    const float* emb  = (const float*)d_in[0];
    const float* Wfc  = (const float*)d_in[1];
    const float* attn = (const float*)d_in[2];
    const int*   src  = (const int*)d_in[3];
    const int*   dst  = (const int*)d_in[4];
    float* out = (float*)d_out; // [N*H] h, then [1] loss

    char* p = (char*)d_ws;
    int*   deg     = (int*)p;   p += (size_t)NNODES * 4;
    float* lossAcc = (float*)p; p += 256;            // adjacent to deg: one fused memset
    int*   cursor  = (int*)p;   p += (size_t)NNODES * 4;
    int*   row_ptr = (int*)p;   p += (size_t)(NNODES + 1) * 4;
    int*   bsums   = (int*)p;   p += (size_t)SCAN_NB * 4;
    int*   boffs   = (int*)p;   p += (size_t)SCAN_NB * 4;
    p = (char*)(((size_t)p + 255) & ~(size_t)255);
    int2*  csr     = (int2*)p;  p += (size_t)NEDGES * 8;
    float* att_csr = (float*)p; p += (size_t)NEDGES * 4;
    float* zs0     = (float*)p; p += (size_t)NNODES * 4;
    float* zd0     = (float*)p; p += (size_t)NNODES * 4;
    float* zs1     = (float*)p; p += (size_t)NNODES * 4;
    float* zd1     = (float*)p; p += (size_t)NNODES * 4;
    float* wsv     = (float*)p; p += 64 * 4;
    float* wdv     = (float*)p; p += 64 * 4;
    p = (char*)(((size_t)p + 255) & ~(size_t)255);
    float* h1      = (float*)p; p += (size_t)NNODES * HDIM * 4;

    hipMemsetAsync(deg, 0, (size_t)NNODES * 4 + 256, stream);  // deg + lossAcc

    const int E4B = (NEDGES / 4 + 255) / 256;
    const int NB = (NNODES + 3) / 4;   // 4 waves/block, 1 node per wave

    k_count<<<E4B, 256, 0, stream>>>((const int4*)dst, deg);
    k_scan1<<<SCAN_NB, SCAN_B, 0, stream>>>(deg, bsums);
    k_scan2<<<1, SCAN_B, 0, stream>>>(bsums, boffs, Wfc, attn, wsv, wdv);
    k_scan3<<<SCAN_NB, SCAN_B, 0, stream>>>(deg, boffs, row_ptr, cursor);
    k_fill<<<E4B, 256, 0, stream>>>((const int4*)src, (const int4*)dst, cursor, csr);
    k_zinit<<<NB, 256, 0, stream>>>(emb, wsv, wdv, zs0, zd0);

    // layer 1: h_in = emb -> h1, compute zs1/zd1
    k_layer<false, true><<<NB, 256, 0, stream>>>(emb, emb, row_ptr, csr, zs0, zd0,
                                                 att_csr, h1, wsv, wdv, zs1, zd1);
    // layer 2: h_in = h1 -> out (final h), store att
    k_layer<true, false><<<NB, 256, 0, stream>>>(h1, emb, row_ptr, csr, zs1, zd1,
                                                 att_csr, out, wsv, wdv, zs0, zd0);

    k_loss2<<<2048, 256, 0, stream>>>(out, emb, csr, att_csr, lossAcc);
    k_finalize<<<1, 1, 0, stream>>>(lossAcc, out + (size_t)NNODES * HDIM);
}

// Round 5
// 293.336 us; speedup vs baseline: 3.6179x; 1.0326x over previous
//
#include <hip/hip_runtime.h>

#define NNODES 50000
#define NEDGES 800000
#define HDIM 64
#define GAMMA 0.2f
#define SCAN_B 256
#define SCAN_NB ((NNODES + SCAN_B - 1) / SCAN_B)   // 196

typedef unsigned short u16;

__device__ __forceinline__ float wave_sum(float v) {
    #pragma unroll
    for (int off = 32; off; off >>= 1) v += __shfl_xor(v, off, 64);
    return v;
}
__device__ __forceinline__ float wave_max(float v) {
    #pragma unroll
    for (int off = 32; off; off >>= 1) v = fmaxf(v, __shfl_xor(v, off, 64));
    return v;
}
__device__ __forceinline__ int wave_sum_i(int v) {
    #pragma unroll
    for (int off = 32; off; off >>= 1) v += __shfl_xor(v, off, 64);
    return v;
}
__device__ __forceinline__ float group16_sum(float v) {
    v += __shfl_xor(v, 1, 64);
    v += __shfl_xor(v, 2, 64);
    v += __shfl_xor(v, 4, 64);
    v += __shfl_xor(v, 8, 64);
    return v;
}

// zs[n] = h[n]·ws, zd[n] = h[n]·wd  (wave per node) + contiguous dst_map fill
__global__ __launch_bounds__(256) void k_zinit(const float* __restrict__ h,
                                               const float* __restrict__ ws,
                                               const float* __restrict__ wd,
                                               const int* __restrict__ row_ptr,
                                               u16* __restrict__ dst_map,
                                               float* __restrict__ zs, float* __restrict__ zd) {
    int wid = (blockIdx.x * blockDim.x + threadIdx.x) >> 6;
    int lane = threadIdx.x & 63;
    if (wid >= NNODES) return;
    float v = h[wid * HDIM + lane];
    float a = wave_sum(v * ws[lane]);
    float b = wave_sum(v * wd[lane]);
    if (lane == 0) { zs[wid] = a; zd[wid] = b; }
    int s0 = row_ptr[wid], s1 = row_ptr[wid + 1];
    for (int base = s0; base < s1; base += 64) {
        int i = base + lane;
        if (i < s1) dst_map[i] = (u16)wid;
    }
}

// 4 edges per thread via int4
__global__ __launch_bounds__(256) void k_count(const int4* __restrict__ dst4, int* __restrict__ deg) {
    int k = blockIdx.x * blockDim.x + threadIdx.x;
    if (k >= NEDGES / 4) return;
    int4 d = dst4[k];
    atomicAdd(&deg[d.x], 1);
    atomicAdd(&deg[d.y], 1);
    atomicAdd(&deg[d.z], 1);
    atomicAdd(&deg[d.w], 1);
}

// --- hierarchical scan: deg -> row_ptr (exclusive), cursor ---
__global__ __launch_bounds__(SCAN_B) void k_scan1(const int* __restrict__ deg,
                                                  int* __restrict__ blockSums) {
    int t = threadIdx.x;
    int idx = blockIdx.x * SCAN_B + t;
    int v = (idx < NNODES) ? deg[idx] : 0;
    int ws = wave_sum_i(v);
    __shared__ int part[4];
    if ((t & 63) == 0) part[t >> 6] = ws;
    __syncthreads();
    if (t == 0) blockSums[blockIdx.x] = part[0] + part[1] + part[2] + part[3];
}

// scan of block sums + (fused) ws/wd precompute
__global__ __launch_bounds__(SCAN_B) void k_scan2(int* __restrict__ blockSums,
                                                  int* __restrict__ blockOffs,
                                                  const float* __restrict__ Wfc,
                                                  const float* __restrict__ attn,
                                                  float* __restrict__ wsv,
                                                  float* __restrict__ wdv) {
    int t = threadIdx.x;
    if (t < 128) {
        int k = t & 63;
        const float* av = attn + ((t >= 64) ? HDIM : 0);
        float s = 0.f;
        for (int j = 0; j < HDIM; ++j) s += Wfc[j * HDIM + k] * av[j];
        if (t < 64) wsv[k] = s; else wdv[k] = s;
    }
    __shared__ int s[SCAN_B];
    int v = (t < SCAN_NB) ? blockSums[t] : 0;
    s[t] = v;
    __syncthreads();
    for (int off = 1; off < SCAN_B; off <<= 1) {
        int x = (t >= off) ? s[t - off] : 0;
        __syncthreads();
        s[t] += x;
        __syncthreads();
    }
    if (t < SCAN_NB) blockOffs[t] = s[t] - v;   // exclusive
}

__global__ __launch_bounds__(SCAN_B) void k_scan3(const int* __restrict__ deg,
                                                  const int* __restrict__ blockOffs,
                                                  int* __restrict__ row_ptr,
                                                  int* __restrict__ cursor) {
    __shared__ int s[SCAN_B];
    int t = threadIdx.x;
    int idx = blockIdx.x * SCAN_B + t;
    int v = (idx < NNODES) ? deg[idx] : 0;
    s[t] = v;
    __syncthreads();
    for (int off = 1; off < SCAN_B; off <<= 1) {
        int x = (t >= off) ? s[t - off] : 0;
        __syncthreads();
        s[t] += x;
        __syncthreads();
    }
    if (idx < NNODES) {
        int excl = s[t] - v + blockOffs[blockIdx.x];
        row_ptr[idx] = excl;
        cursor[idx] = excl;
    }
    if (idx == 0) row_ptr[NNODES] = NEDGES;
}

// 4 edges per thread; u16 src payload only (2B scattered stores)
__global__ __launch_bounds__(256) void k_fill(const int4* __restrict__ src4,
                                              const int4* __restrict__ dst4,
                                              int* __restrict__ cursor, u16* __restrict__ csr_src) {
    int k = blockIdx.x * blockDim.x + threadIdx.x;
    if (k >= NEDGES / 4) return;
    int4 s = src4[k];
    int4 d = dst4[k];
    int p0 = atomicAdd(&cursor[d.x], 1); csr_src[p0] = (u16)s.x;
    int p1 = atomicAdd(&cursor[d.y], 1); csr_src[p1] = (u16)s.y;
    int p2 = atomicAdd(&cursor[d.z], 1); csr_src[p2] = (u16)s.z;
    int p3 = atomicAdd(&cursor[d.w], 1); csr_src[p3] = (u16)s.w;
}

// One wave per node; single-pass register-resident softmax for deg<=64,
// unrolled gather with 4 row loads in flight.
template <bool STORE_ATT, bool COMPUTE_Z>
__global__ __launch_bounds__(256) void k_layer(const float* __restrict__ h_in,
                                               const float* __restrict__ emb,
                                               const int* __restrict__ row_ptr,
                                               const u16* __restrict__ csr_src,
                                               const float* __restrict__ zs,
                                               const float* __restrict__ zd,
                                               float* __restrict__ att_csr,
                                               float* __restrict__ h_out,
                                               const float* __restrict__ ws,
                                               const float* __restrict__ wd,
                                               float* __restrict__ zs_out,
                                               float* __restrict__ zd_out) {
    int wid = (blockIdx.x * blockDim.x + threadIdx.x) >> 6;
    int lane = threadIdx.x & 63;
    if (wid >= NNODES) return;
    int s0 = row_ptr[wid], s1 = row_ptr[wid + 1];
    int ne = s1 - s0;
    float zdn = zd[wid];
    const int sub = lane >> 4, q16 = lane & 15;
    float4 acc = make_float4(0.f, 0.f, 0.f, 0.f);
    float inv;

    if (ne <= 64) {
        // ---- fast path: everything register-resident ----
        int s = 0; float e = -INFINITY;
        bool valid = lane < ne;
        if (valid) {
            s = csr_src[s0 + lane];
            float z = zs[s] + zdn;
            e = z > 0.f ? z : GAMMA * z;
        }
        float m = wave_max(e);
        float ex = valid ? __expf(e - m) : 0.f;
        float dsum = wave_sum(ex);
        inv = 1.f / fmaxf(dsum, 1e-16f);
        if (STORE_ATT && valid) att_csr[s0 + lane] = ex * inv;
        for (int j = 0; j < ne; j += 16) {
            int j0 = j + sub, j1 = j + 4 + sub, j2 = j + 8 + sub, j3 = j + 12 + sub;
            float w0 = __shfl(ex, j0, 64), w1 = __shfl(ex, j1, 64);
            float w2 = __shfl(ex, j2, 64), w3 = __shfl(ex, j3, 64);
            int t0 = __shfl(s, j0, 64), t1 = __shfl(s, j1, 64);
            int t2 = __shfl(s, j2, 64), t3 = __shfl(s, j3, 64);
            const float4 r0 = *(const float4*)&h_in[(size_t)t0 * HDIM + 4 * q16];
            const float4 r1 = *(const float4*)&h_in[(size_t)t1 * HDIM + 4 * q16];
            const float4 r2 = *(const float4*)&h_in[(size_t)t2 * HDIM + 4 * q16];
            const float4 r3 = *(const float4*)&h_in[(size_t)t3 * HDIM + 4 * q16];
            acc.x += w0 * r0.x + w1 * r1.x + w2 * r2.x + w3 * r3.x;
            acc.y += w0 * r0.y + w1 * r1.y + w2 * r2.y + w3 * r3.y;
            acc.z += w0 * r0.z + w1 * r1.z + w2 * r2.z + w3 * r3.z;
            acc.w += w0 * r0.w + w1 * r1.w + w2 * r2.w + w3 * r3.w;
        }
    } else {
        // ---- generic 3-phase path (deg > 64; statistically never here) ----
        float m = -INFINITY;
        for (int base = s0; base < s1; base += 64) {
            int i = base + lane;
            if (i < s1) {
                int s = csr_src[i];
                float z = zs[s] + zdn;
                z = z > 0.f ? z : GAMMA * z;
                m = fmaxf(m, z);
            }
        }
        m = wave_max(m);
        float dsum = 0.f;
        for (int base = s0; base < s1; base += 64) {
            int i = base + lane;
            if (i < s1) {
                int s = csr_src[i];
                float z = zs[s] + zdn;
                z = z > 0.f ? z : GAMMA * z;
                dsum += __expf(z - m);
            }
        }
        dsum = wave_sum(dsum);
        inv = 1.f / fmaxf(dsum, 1e-16f);
        for (int base = s0; base < s1; base += 64) {
            int i = base + lane;
            float ex = 0.f; int s = 0;
            if (i < s1) {
                s = csr_src[i];
                float z = zs[s] + zdn;
                z = z > 0.f ? z : GAMMA * z;
                ex = __expf(z - m);
                if (STORE_ATT) att_csr[i] = ex * inv;
            }
            int nc = min(64, s1 - base);
            for (int j = 0; j < nc; j += 16) {
                int j0 = j + sub, j1 = j + 4 + sub, j2 = j + 8 + sub, j3 = j + 12 + sub;
                float w0 = __shfl(ex, j0, 64), w1 = __shfl(ex, j1, 64);
                float w2 = __shfl(ex, j2, 64), w3 = __shfl(ex, j3, 64);
                int t0 = __shfl(s, j0, 64), t1 = __shfl(s, j1, 64);
                int t2 = __shfl(s, j2, 64), t3 = __shfl(s, j3, 64);
                const float4 r0 = *(const float4*)&h_in[(size_t)t0 * HDIM + 4 * q16];
                const float4 r1 = *(const float4*)&h_in[(size_t)t1 * HDIM + 4 * q16];
                const float4 r2 = *(const float4*)&h_in[(size_t)t2 * HDIM + 4 * q16];
                const float4 r3 = *(const float4*)&h_in[(size_t)t3 * HDIM + 4 * q16];
                acc.x += w0 * r0.x + w1 * r1.x + w2 * r2.x + w3 * r3.x;
                acc.y += w0 * r0.y + w1 * r1.y + w2 * r2.y + w3 * r3.y;
                acc.z += w0 * r0.z + w1 * r1.z + w2 * r2.z + w3 * r3.z;
                acc.w += w0 * r0.w + w1 * r1.w + w2 * r2.w + w3 * r3.w;
            }
        }
    }
    // reduce partial sums across the 4 sub-groups
    #pragma unroll
    for (int off = 16; off <= 32; off <<= 1) {
        acc.x += __shfl_xor(acc.x, off, 64);
        acc.y += __shfl_xor(acc.y, off, 64);
        acc.z += __shfl_xor(acc.z, off, 64);
        acc.w += __shfl_xor(acc.w, off, 64);
    }
    const float4 ev = *(const float4*)&emb[(size_t)wid * HDIM + 4 * q16];
    float4 hv;
    hv.x = 0.5f * (ev.x + acc.x * inv);
    hv.y = 0.5f * (ev.y + acc.y * inv);
    hv.z = 0.5f * (ev.z + acc.z * inv);
    hv.w = 0.5f * (ev.w + acc.w * inv);
    if (sub == 0) *(float4*)&h_out[(size_t)wid * HDIM + 4 * q16] = hv;
    if (COMPUTE_Z) {
        float pa = 0.f, pb = 0.f;
        if (sub == 0) {
            const float4 w4 = *(const float4*)&ws[4 * q16];
            const float4 d4 = *(const float4*)&wd[4 * q16];
            pa = hv.x * w4.x + hv.y * w4.y + hv.z * w4.z + hv.w * w4.w;
            pb = hv.x * d4.x + hv.y * d4.y + hv.z * d4.z + hv.w * d4.w;
        }
        float a = wave_sum(pa);
        float b = wave_sum(pb);
        if (lane == 0) { zs_out[wid] = a; zd_out[wid] = b; }
    }
}

// Edge-parallel fused loss, u16 indices, 2x unrolled
__global__ __launch_bounds__(256) void k_loss2(const float* __restrict__ h,
                                               const float* __restrict__ emb,
                                               const u16* __restrict__ csr_src,
                                               const u16* __restrict__ dst_map,
                                               const float* __restrict__ att_csr,
                                               float* __restrict__ acc) {
    const int lane = threadIdx.x & 63;
    const int wib = threadIdx.x >> 6;
    const int gw = (blockIdx.x * blockDim.x + threadIdx.x) >> 6;
    const int nwaves = (gridDim.x * blockDim.x) >> 6;
    const int sub = lane >> 4, q16 = lane & 15;
    float lb = 0.f;

    // loss_a: nodes, 4 per wave
    for (int g = gw; g < NNODES / 4; g += nwaves) {
        int n = g * 4 + sub;
        const float4 hv = *(const float4*)&h[(size_t)n * HDIM + 4 * q16];
        const float4 ev = *(const float4*)&emb[(size_t)n * HDIM + 4 * q16];
        float dx = hv.x - ev.x, dy = hv.y - ev.y, dz = hv.z - ev.z, dw = hv.w - ev.w;
        float ss = group16_sum(dx * dx + dy * dy + dz * dz + dw * dw);
        if (q16 == 0) lb += 0.5f * ss;
    }
    // loss_b: edges, 8 per wave (2 per 16-lane group)
    for (int g = gw; g < NEDGES / 8; g += nwaves) {
        int e0 = g * 8 + sub;
        int e1 = e0 + 4;
        int s0i = csr_src[e0], d0i = dst_map[e0];
        int s1i = csr_src[e1], d1i = dst_map[e1];
        const float4 hs0 = *(const float4*)&h[(size_t)s0i * HDIM + 4 * q16];
        const float4 hd0 = *(const float4*)&h[(size_t)d0i * HDIM + 4 * q16];
        const float4 hs1 = *(const float4*)&h[(size_t)s1i * HDIM + 4 * q16];
        const float4 hd1 = *(const float4*)&h[(size_t)d1i * HDIM + 4 * q16];
        float ax = hd0.x - hs0.x, ay = hd0.y - hs0.y, az = hd0.z - hs0.z, aw = hd0.w - hs0.w;
        float bx = hd1.x - hs1.x, by = hd1.y - hs1.y, bz = hd1.z - hs1.z, bw = hd1.w - hs1.w;
        float ss0 = group16_sum(ax * ax + ay * ay + az * az + aw * aw);
        float ss1 = group16_sum(bx * bx + by * by + bz * bz + bw * bw);
        if (q16 == 0)
            lb += 0.5f * (att_csr[e0] * sqrtf(ss0 + 1e-12f) +
                          att_csr[e1] * sqrtf(ss1 + 1e-12f));
    }
    lb = wave_sum(lb);
    __shared__ float part[4];
    if (lane == 0) part[wib] = lb;
    __syncthreads();
    if (threadIdx.x == 0)
        atomicAdd(acc, part[0] + part[1] + part[2] + part[3]);
}

__global__ void k_finalize(const float* __restrict__ acc, float* __restrict__ out_loss) {
    out_loss[0] = acc[0] / (float)NNODES;
}

extern "C" void kernel_launch(void* const* d_in, const int* in_sizes, int n_in,
                              void* d_out, int out_size, void* d_ws, size_t ws_size,
                              hipStream_t stream) {
    const float* emb  = (const float*)d_in[0];
    const float* Wfc  = (const float*)d_in[1];
    const float* attn = (const float*)d_in[2];
    const int*   src  = (const int*)d_in[3];
    const int*   dst  = (const int*)d_in[4];
    float* out = (float*)d_out; // [N*H] h, then [1] loss

    char* p = (char*)d_ws;
    int*   deg     = (int*)p;   p += (size_t)NNODES * 4;
    float* lossAcc = (float*)p; p += 256;            // adjacent to deg: one fused memset
    int*   cursor  = (int*)p;   p += (size_t)NNODES * 4;
    int*   row_ptr = (int*)p;   p += (size_t)(NNODES + 1) * 4;
    int*   bsums   = (int*)p;   p += (size_t)SCAN_NB * 4;
    int*   boffs   = (int*)p;   p += (size_t)SCAN_NB * 4;
    p = (char*)(((size_t)p + 255) & ~(size_t)255);
    u16*   csr_src = (u16*)p;   p += (size_t)NEDGES * 2;
    u16*   dst_map = (u16*)p;   p += (size_t)NEDGES * 2;
    float* att_csr = (float*)p; p += (size_t)NEDGES * 4;
    float* zs0     = (float*)p; p += (size_t)NNODES * 4;
    float* zd0     = (float*)p; p += (size_t)NNODES * 4;
    float* zs1     = (float*)p; p += (size_t)NNODES * 4;
    float* zd1     = (float*)p; p += (size_t)NNODES * 4;
    float* wsv     = (float*)p; p += 64 * 4;
    float* wdv     = (float*)p; p += 64 * 4;
    p = (char*)(((size_t)p + 255) & ~(size_t)255);
    float* h1      = (float*)p; p += (size_t)NNODES * HDIM * 4;

    hipMemsetAsync(deg, 0, (size_t)NNODES * 4 + 256, stream);  // deg + lossAcc

    const int E4B = (NEDGES / 4 + 255) / 256;
    const int NB = (NNODES + 3) / 4;   // 4 waves/block, 1 node per wave

    k_count<<<E4B, 256, 0, stream>>>((const int4*)dst, deg);
    k_scan1<<<SCAN_NB, SCAN_B, 0, stream>>>(deg, bsums);
    k_scan2<<<1, SCAN_B, 0, stream>>>(bsums, boffs, Wfc, attn, wsv, wdv);
    k_scan3<<<SCAN_NB, SCAN_B, 0, stream>>>(deg, boffs, row_ptr, cursor);
    k_fill<<<E4B, 256, 0, stream>>>((const int4*)src, (const int4*)dst, cursor, csr_src);
    k_zinit<<<NB, 256, 0, stream>>>(emb, wsv, wdv, row_ptr, dst_map, zs0, zd0);

    // layer 1: h_in = emb -> h1, compute zs1/zd1
    k_layer<false, true><<<NB, 256, 0, stream>>>(emb, emb, row_ptr, csr_src, zs0, zd0,
                                                 att_csr, h1, wsv, wdv, zs1, zd1);
    // layer 2: h_in = h1 -> out (final h), store att
    k_layer<true, false><<<NB, 256, 0, stream>>>(h1, emb, row_ptr, csr_src, zs1, zd1,
                                                 att_csr, out, wsv, wdv, zs0, zd0);

    k_loss2<<<2048, 256, 0, stream>>>(out, emb, csr_src, dst_map, att_csr, lossAcc);
    k_finalize<<<1, 1, 0, stream>>>(lossAcc, out + (size_t)NNODES * HDIM);
}